// Round 13
// baseline (349.628 us; speedup 1.0000x reference)
//
#include <hip/hip_runtime.h>
#include <hip/hip_bf16.h>
#include <hip/hip_fp16.h>

#define NF 100000
#define NH 49152
#define EDG 400000
#define SLOTD 24
#define SLOTE 32
#define FILLB 1563   /* (EDG+255)/256 */

typedef __attribute__((ext_vector_type(8))) short short8;
typedef __attribute__((ext_vector_type(4))) float float4v;
typedef unsigned short u16;
typedef unsigned int u32;

__device__ __forceinline__ u16 f2b(float x) {
    u32 u = __float_as_uint(x);
    u32 r = u + 0x7FFFu + ((u >> 16) & 1u);
    return (u16)(r >> 16);
}
// packed f32x2 -> bf16x2 in one VALU op (lo -> bits[15:0], hi -> bits[31:16])
__device__ __forceinline__ u32 cvt_pk(float lo, float hi) {
    u32 r;
    asm("v_cvt_pk_bf16_f32 %0, %1, %2" : "=v"(r) : "v"(lo), "v"(hi));
    return r;
}
__device__ __forceinline__ __half2 h2(u32 v) { union { u32 u; __half2 h; } c; c.u = v; return c.h; }
// 5-op tanh: exp2(x*2log2e) -> t; 1 - 2*rcp(t+1)
__device__ __forceinline__ float fast_tanh(float x) {
    float t = __builtin_amdgcn_exp2f(x * 2.885390081777927f);
    return fmaf(-2.0f, __builtin_amdgcn_rcpf(t + 1.0f), 1.0f);
}

// ---------------- Kernel A: fill_enc (atomics) ∪ init_small ∪ m zero rows ----------------
__global__ __launch_bounds__(256) void init_fill_enc(
    const int* __restrict__ enc_src, const int* __restrict__ enc_dst,
    const int* __restrict__ dec_src,
    int* __restrict__ cntE, u32* __restrict__ csrE,
    float* __restrict__ deg_se, float* __restrict__ deg_sd,
    const float* __restrict__ W_dec, const float* __restrict__ W_a1,
    u16* __restrict__ fragWdec, u16* __restrict__ fragWa1,
    const float* __restrict__ W_lin, const float* __restrict__ b_lin,
    const float* __restrict__ b_a1, const float* __restrict__ W_o,
    float* __restrict__ uvs, const float* __restrict__ W_a2,
    float* __restrict__ gtab, u32* __restrict__ mzero, int zstride) {
    __shared__ float uvl[256];
    const int b = blockIdx.x;
    if (b < FILLB) {
        int e = b * 256 + threadIdx.x;
        if (e >= EDG) return;
        int es = enc_src[e], ed = enc_dst[e], ds = dec_src[e];
        int i2 = atomicAdd(&cntE[ed], 1);
        atomicAdd(&deg_se[es], 1.0f);
        atomicAdd(&deg_sd[ds], 1.0f);
        if (i2 < SLOTE) csrE[(size_t)ed * SLOTE + i2] = (u32)es;
        return;
    }
    const int b2 = b - FILLB;
    if (b2 < 28) {
        int gid = b2 * 256 + threadIdx.x;   // 0..7167
        if (gid >= 7168) return;
        int L = gid & 63;
        int f = gid >> 6;          // 0..95: W_dec (t=f>>3); 96..111: W_a1
        int q = L >> 4, cb = L & 15;
        if (f < 96) {
            int fr = f & 7;
            int c = fr >> 1, kc = fr & 1;
            int k0 = kc * 32 + q * 8;
            int nn = c * 16 + cb;
            int t = f >> 3;
            #pragma unroll
            for (int j = 0; j < 8; ++j)
                fragWdec[(f * 64 + L) * 8 + j] = f2b(W_dec[t * 4096 + (k0 + j) * 64 + nn]);
        } else {
            int fr = f - 96;
            int c2 = fr >> 1, kc = fr & 1;
            int k0 = kc * 32 + q * 8;
            int nn = c2 * 16 + cb;
            #pragma unroll
            for (int j = 0; j < 8; ++j)
                fragWa1[(fr * 64 + L) * 8 + j] = f2b(W_a1[(k0 + j) * 128 + nn]);
        }
    } else if (b2 == 28) {
        // uvs for dec_scan
        int k = threadIdx.x;
        if (k < 128) {
            float su = 0.f, sv = 0.f;
            for (int h = 0; h < 64; ++h) {
                su = fmaf(W_lin[h], W_a1[h * 128 + k], su);
                sv = fmaf(b_lin[h], W_a1[h * 128 + k], sv);
            }
            uvs[k] = su;
            uvs[128 + k] = sv + b_a1[k];
            if (k == 0) {
                float a = 0.f, bb = 0.f;
                for (int h = 0; h < 64; ++h) {
                    a = fmaf(W_lin[h], W_o[h], a);
                    bb = fmaf(b_lin[h], W_o[h], bb);
                }
                uvs[256] = a;  // wlo
                uvs[257] = bb; // blo
            }
        }
    } else if (b2 == 94) {
        // zero the 3 chunk zero-rows of m (384 u32 total; zstride=0 in fallback)
        for (int j = threadIdx.x; j < 384; j += 256)
            mzero[(j >> 7) * (size_t)zstride + (j & 127)] = 0u;
    } else {
        // gtab blocks (b2 = 29..93): recompute u,v locally (no cross-block dependency)
        int k = threadIdx.x;
        if (k < 128) {
            float su = 0.f, sv = 0.f;
            for (int h = 0; h < 64; ++h) {
                su = fmaf(W_lin[h], W_a1[h * 128 + k], su);
                sv = fmaf(b_lin[h], W_a1[h * 128 + k], sv);
            }
            uvl[k] = su;
            uvl[128 + k] = sv + b_a1[k];
        }
        __syncthreads();
        int i = (b2 - 29) * 256 + threadIdx.x;
        if (i <= 16384) {
            float y = fmaf((float)i, 1.f / 256.f, -32.f);
            float s = 0.f;
            for (int kk = 0; kk < 128; ++kk)
                s = fmaf(fast_tanh(fmaf(y, uvl[kk], uvl[128 + kk])), W_a2[kk], s);
            gtab[i] = s;
        }
    }
}

// ---------------- standalone fill_dec (fallback path) ----------------
__global__ void fill_dec(const int* __restrict__ dec_src, const int* __restrict__ dec_dst,
                         int* __restrict__ cntD, u16* __restrict__ csrD) {
    int e = blockIdx.x * 256 + threadIdx.x;
    if (e >= EDG) return;
    int ds = dec_src[e], dd = dec_dst[e];
    int i1 = atomicAdd(&cntD[dd], 1);
    if (i1 < SLOTD) csrD[(size_t)dd * SLOTD + i1] = (u16)(ds + 1);   // 0 = empty
}

// ---------------- Kernel B: fill_dec (blocks 0..FILLB-1) ∪ enc_make ----------------
__global__ __launch_bounds__(256) void enc_make_fill_dec(
    const int* __restrict__ dec_src, const int* __restrict__ dec_dst,
    int* __restrict__ cntD, u16* __restrict__ csrD,
    const float* __restrict__ feat, const float* __restrict__ deg_se,
    const int* __restrict__ cntE, const u32* __restrict__ csrE,
    const float* __restrict__ deg_sd, const float* __restrict__ W_enc,
    const float* __restrict__ b_enc, const float* __restrict__ W_proc,
    const float* __restrict__ b_proc, u16* __restrict__ m, size_t cstride) {
    __shared__ __align__(16) float aggl[4][12];
    const int b = blockIdx.x;
    if (b < FILLB) {
        int e = b * 256 + threadIdx.x;
        if (e >= EDG) return;
        int ds = dec_src[e], dd = dec_dst[e];
        int i1 = atomicAdd(&cntD[dd], 1);
        if (i1 < SLOTD) csrD[(size_t)dd * SLOTD + i1] = (u16)(ds + 1);
        return;
    }
    const int tid = threadIdx.x, lane = tid & 63, wid = tid >> 6;
    const int n = (b - FILLB) * 4 + wid;          // one node per wave
    const int q = lane >> 2, l = lane & 3;        // 16 edge slots x 4 lanes
    int cntRaw = cntE[n];
    int cnt = cntRaw > SLOTE ? SLOTE : cntRaw;
    const u32* cp = csrE + (size_t)n * SLOTE;
    float4 a = {0.f, 0.f, 0.f, 0.f};
    if (l < 3) {
        for (int e = q; e < cnt; e += 16) {
            u32 s = cp[e];
            float c = rsqrtf(fmaxf(deg_se[s], 1.0f));
            float4 w = *(const float4*)(feat + (size_t)s * 12 + l * 4);
            w.x = (w.x != w.x) ? 0.f : w.x; w.y = (w.y != w.y) ? 0.f : w.y;
            w.z = (w.z != w.z) ? 0.f : w.z; w.w = (w.w != w.w) ? 0.f : w.w;
            a.x = fmaf(w.x, c, a.x); a.y = fmaf(w.y, c, a.y);
            a.z = fmaf(w.z, c, a.z); a.w = fmaf(w.w, c, a.w);
        }
    }
    // reduce across the 16 slots (lane bits 2..5)
    #pragma unroll
    for (int mm = 4; mm < 64; mm <<= 1) {
        a.x += __shfl_xor(a.x, mm); a.y += __shfl_xor(a.y, mm);
        a.z += __shfl_xor(a.z, mm); a.w += __shfl_xor(a.w, mm);
    }
    if (q == 0 && l < 3) *(float4*)(&aggl[wid][l * 4]) = a;
    asm volatile("s_waitcnt lgkmcnt(0)" ::: "memory");   // wave-local LDS ready

    const int h = lane;
    float cde = rsqrtf(fmaxf((float)cntRaw, 1.0f));
    float csd = rsqrtf(fmaxf(deg_sd[n], 1.0f));
    float he[12];
    #pragma unroll
    for (int ti = 0; ti < 12; ++ti) {
        float av = aggl[wid][ti] * cde;
        float x = fmaf(av, W_enc[ti * 64 + h], b_enc[ti * 64 + h]);
        he[ti] = x > 0.f ? x : 0.01f * x;
    }
    #pragma unroll
    for (int c = 0; c < 3; ++c) {
        float s0v[4];
        #pragma unroll
        for (int tt = 0; tt < 4; ++tt) {
            int t = c * 4 + tt;
            float s = b_proc[t];
            #pragma unroll
            for (int ti = 0; ti < 12; ++ti) s = fmaf(he[ti], W_proc[ti * 12 + t], s);
            s0v[tt] = fmaxf(s, 0.f) * csd;
        }
        u16 r0 = __half_as_ushort(__float2half(s0v[0]));
        u16 r1 = __half_as_ushort(__float2half(s0v[1]));
        u16 r2 = __half_as_ushort(__float2half(s0v[2]));
        u16 r3 = __half_as_ushort(__float2half(s0v[3]));
        u32 o0 = ((u32)r1 << 16) | r0;
        u32 o1 = ((u32)r3 << 16) | r2;
        u32* dst = (u32*)(m + c * cstride + (size_t)(n + 1) * 256 + h * 4);
        dst[0] = o0; dst[1] = o1;
    }
}

// ---------------- fallback pieces (small-workspace path) ----------------
__global__ __launch_bounds__(256) void enc_gather(const float* __restrict__ feat,
                                                  const float* __restrict__ deg_se,
                                                  const int* __restrict__ cntE,
                                                  const u32* __restrict__ csrE,
                                                  float* __restrict__ agg) {
    const int tid = threadIdx.x, lane = tid & 63, wid = tid >> 6;
    const int grp = lane >> 2, l = lane & 3;      // 16 quads of 4 lanes
    const int dst = blockIdx.x * 64 + wid * 16 + grp;
    int cnt = cntE[dst];
    if (cnt > SLOTE) cnt = SLOTE;
    const u32* cp = csrE + (size_t)dst * SLOTE;
    float4 a = {0.f, 0.f, 0.f, 0.f};
    if (l < 3) {
        for (int e = 0; e < cnt; ++e) {
            u32 s = cp[e];
            float c = rsqrtf(fmaxf(deg_se[s], 1.0f));
            float4 w = *(const float4*)(feat + (size_t)s * 12 + l * 4);
            w.x = (w.x != w.x) ? 0.f : w.x; w.y = (w.y != w.y) ? 0.f : w.y;
            w.z = (w.z != w.z) ? 0.f : w.z; w.w = (w.w != w.w) ? 0.f : w.w;
            a.x = fmaf(w.x, c, a.x); a.y = fmaf(w.y, c, a.y);
            a.z = fmaf(w.z, c, a.z); a.w = fmaf(w.w, c, a.w);
        }
    }
    *(float4*)(agg + (size_t)dst * 16 + l * 4) = a;   // l==3 writes zero pad
}

__global__ void make_chunk(const float* __restrict__ agg, const int* __restrict__ cntE,
                           const float* __restrict__ deg_sd, const float* __restrict__ W_enc,
                           const float* __restrict__ b_enc, const float* __restrict__ W_proc,
                           const float* __restrict__ b_proc, u16* __restrict__ m, int t0) {
    int gid = blockIdx.x * 256 + threadIdx.x;
    if (gid >= NH * 64) return;
    int n = gid >> 6, h = gid & 63;
    float cde = rsqrtf(fmaxf((float)cntE[n], 1.0f));
    float csd = rsqrtf(fmaxf(deg_sd[n], 1.0f));
    float he[12];
    #pragma unroll
    for (int ti = 0; ti < 12; ++ti) {
        float a = agg[n * 16 + ti] * cde;
        float x = fmaf(a, W_enc[ti * 64 + h], b_enc[ti * 64 + h]);
        he[ti] = x > 0.f ? x : 0.01f * x;
    }
    u16 r[4];
    #pragma unroll
    for (int tt = 0; tt < 4; ++tt) {
        int t = t0 + tt;
        float s = b_proc[t];
        #pragma unroll
        for (int ti = 0; ti < 12; ++ti) s = fmaf(he[ti], W_proc[ti * 12 + t], s);
        s = fmaxf(s, 0.f) * csd;
        r[tt] = __half_as_ushort(__float2half(s));
    }
    u32 o0 = ((u32)r[1] << 16) | r[0];
    u32 o1 = ((u32)r[3] << 16) | r[2];
    u32* dst = (u32*)(m + (size_t)(n + 1) * 256 + h * 4);
    dst[0] = o0; dst[1] = o1;
}

// 4-edge accumulate helper (a8 = 8 half2 channels for one node); s==0 -> zero row
__device__ __forceinline__ void acc4(__half2* a8, const u16* mrow, u32 lo, u32 hi) {
    int s0 = (int)(lo & 0xFFFF), s1 = (int)(lo >> 16);
    int s2 = (int)(hi & 0xFFFF), s3 = (int)(hi >> 16);
    const uint4* r0 = (const uint4*)(mrow + (size_t)s0 * 256);
    const uint4* r1 = (const uint4*)(mrow + (size_t)s1 * 256);
    const uint4* r2 = (const uint4*)(mrow + (size_t)s2 * 256);
    const uint4* r3 = (const uint4*)(mrow + (size_t)s3 * 256);
    uint4 A0 = r0[0], B0 = r0[1];
    uint4 A1 = r1[0], B1 = r1[1];
    uint4 A2 = r2[0], B2 = r2[1];
    uint4 A3 = r3[0], B3 = r3[1];
    a8[0] = __hadd2(a8[0], __hadd2(__hadd2(h2(A0.x), h2(A1.x)), __hadd2(h2(A2.x), h2(A3.x))));
    a8[1] = __hadd2(a8[1], __hadd2(__hadd2(h2(A0.y), h2(A1.y)), __hadd2(h2(A2.y), h2(A3.y))));
    a8[2] = __hadd2(a8[2], __hadd2(__hadd2(h2(A0.z), h2(A1.z)), __hadd2(h2(A2.z), h2(A3.z))));
    a8[3] = __hadd2(a8[3], __hadd2(__hadd2(h2(A0.w), h2(A1.w)), __hadd2(h2(A2.w), h2(A3.w))));
    a8[4] = __hadd2(a8[4], __hadd2(__hadd2(h2(B0.x), h2(B1.x)), __hadd2(h2(B2.x), h2(B3.x))));
    a8[5] = __hadd2(a8[5], __hadd2(__hadd2(h2(B0.y), h2(B1.y)), __hadd2(h2(B2.y), h2(B3.y))));
    a8[6] = __hadd2(a8[6], __hadd2(__hadd2(h2(B0.z), h2(B1.z)), __hadd2(h2(B2.z), h2(B3.z))));
    a8[7] = __hadd2(a8[7], __hadd2(__hadd2(h2(B0.w), h2(B1.w)), __hadd2(h2(B2.w), h2(B3.w))));
}

// ---------------- decoder pass: chunk = blockIdx.y; gather + MFMA GEMMs ----------------
// R13: window 0 (edges 0..7) UNCONDITIONAL: empty slots = 0 -> zero row (cache-hot,
// adds 0.0 exactly); invalid nodes additionally scaled by cdd=0 at staging. Removes
// 8 per-node branches -> compiler can batch all 16 row loads -> ~2x memory-level
// parallelism in the phase covering ~100% of nodes. Rest frozen at R12 state.
__global__ __launch_bounds__(256, 4) void dec_batch(
    const u16* __restrict__ mbase, const int* __restrict__ cntD, const u16* __restrict__ csrD,
    const u16* __restrict__ fragWdec, const u16* __restrict__ fragWa1,
    const float* __restrict__ b_dec, const float* __restrict__ b_a1,
    const float* __restrict__ W_a2, const float* __restrict__ W_o,
    float* __restrict__ S1, float* __restrict__ PW, int t0p, size_t mstride) {
    __shared__ __align__(16) u16 zs[18432];   // 4 waves x (4 tt x 16 rows x 72)

    const u16* m = mbase + (size_t)blockIdx.y * mstride;
    const int t0 = t0p + blockIdx.y * 4;
    const int tid = threadIdx.x, lane = tid & 63, wid = tid >> 6;
    const int nw = blockIdx.x * 64 + wid * 16;
    const int g16 = lane >> 4, c16 = lane & 15;
    u16* zw0 = zs + wid * 4608;

    // ---- per-node metadata + first CSR window (8 edges) ----
    int cdw[4]; float cdd[4]; int nnv[4];
    uint4 qa[4];
    #pragma unroll
    for (int k = 0; k < 4; ++k) {
        int n = nw + g16 * 4 + k;
        bool v = (n < NF);
        nnv[k] = v ? n : 0;
        int cd = cntD[nnv[k]];
        cdd[k] = v ? rsqrtf(fmaxf((float)cd, 1.0f)) : 0.f;
        cdw[k] = v ? (cd > SLOTD ? SLOTD : cd) : 0;
        qa[k] = *(const uint4*)(csrD + (size_t)nnv[k] * SLOTD);
    }
    int cdmax = max(max(cdw[0], cdw[1]), max(cdw[2], cdw[3]));

    // acc[k][ch*2 + p]: node k, channel c16*4+ch, tt-pair p
    __half2 acc[4][8];
    #pragma unroll
    for (int k = 0; k < 4; ++k)
        #pragma unroll
        for (int i = 0; i < 8; ++i)
            acc[k][i] = __half2{__half(0.f), __half(0.f)};

    const u16* mrow = m + c16 * 16;
    // window 0: edges 0..7 UNCONDITIONAL (empty slot -> zero row; straight-line
    // code lets the compiler batch all 16 independent row loads)
    #pragma unroll
    for (int k = 0; k < 4; ++k) acc4(acc[k], mrow, qa[k].x, qa[k].y);
    #pragma unroll
    for (int k = 0; k < 4; ++k) acc4(acc[k], mrow, qa[k].z, qa[k].w);
    if (__any(cdmax > 8)) {
        // window 1: edges 8..15 (reuse qa registers)
        #pragma unroll
        for (int k = 0; k < 4; ++k) if (cdw[k] > 8) qa[k] = *(const uint4*)(csrD + (size_t)nnv[k] * SLOTD + 8);
        #pragma unroll
        for (int k = 0; k < 4; ++k) if (cdw[k] > 8) acc4(acc[k], mrow, qa[k].x, qa[k].y);
        #pragma unroll
        for (int k = 0; k < 4; ++k) if (cdw[k] > 12) acc4(acc[k], mrow, qa[k].z, qa[k].w);
        if (__any(cdmax > 16)) {
            // window 2: edges 16..23
            #pragma unroll
            for (int k = 0; k < 4; ++k) if (cdw[k] > 16) qa[k] = *(const uint4*)(csrD + (size_t)nnv[k] * SLOTD + 16);
            #pragma unroll
            for (int k = 0; k < 4; ++k) if (cdw[k] > 16) acc4(acc[k], mrow, qa[k].x, qa[k].y);
            #pragma unroll
            for (int k = 0; k < 4; ++k) if (cdw[k] > 20) acc4(acc[k], mrow, qa[k].z, qa[k].w);
        }
    }

    // ---- stage all 4 tt into LDS (A-operand layout per tt, stride 72) ----
    #pragma unroll
    for (int k = 0; k < 4; ++k) {
        int j = g16 * 4 + k;
        float s = cdd[k];
        #pragma unroll
        for (int p = 0; p < 2; ++p) {
            float2 c0 = __half22float2(acc[k][0 * 2 + p]);
            float2 c1 = __half22float2(acc[k][1 * 2 + p]);
            float2 c2 = __half22float2(acc[k][2 * 2 + p]);
            float2 c3 = __half22float2(acc[k][3 * 2 + p]);
            u32 oA0 = cvt_pk(c0.x * s, c1.x * s);
            u32 oA1 = cvt_pk(c2.x * s, c3.x * s);
            u32 oB0 = cvt_pk(c0.y * s, c1.y * s);
            u32 oB1 = cvt_pk(c2.y * s, c3.y * s);
            u32* dA = (u32*)(zw0 + (2 * p) * 1152 + j * 72 + c16 * 4);
            u32* dB = (u32*)(zw0 + (2 * p + 1) * 1152 + j * 72 + c16 * 4);
            dA[0] = oA0; dA[1] = oA1;
            dB[0] = oB0; dB[1] = oB1;
        }
    }
    asm volatile("s_waitcnt lgkmcnt(0)" ::: "memory");   // wave-local zs ready

    // ---- t-invariant per-lane weights hoisted out of the tt loop ----
    float baw[8], waw[8], wov[4];
    #pragma unroll
    for (int c8 = 0; c8 < 8; ++c8) {
        int k = c8 * 16 + c16;
        baw[c8] = b_a1[k];
        waw[c8] = W_a2[k];
    }
    #pragma unroll
    for (int cc = 0; cc < 4; ++cc) wov[cc] = W_o[cc * 16 + c16];

    // ---- per-t GEMM pipeline (B-fragments streamed from L2; no __syncthreads) ----
    for (int tt = 0; tt < 4; ++tt) {
        const int t = t0 + tt;
        u16* zw = zw0 + tt * 1152;
        const u16* ab = zw + c16 * 72 + g16 * 8;
        short8 a0 = *(const short8*)ab;            // A[m=c16][k=g16*8+j]
        short8 a1 = *(const short8*)(ab + 32);     // k += 32

        const u16* fw = fragWdec + (size_t)t * 4096;
        float4v C1[4];
        #pragma unroll
        for (int cc = 0; cc < 4; ++cc) {
            float4v z4 = {0.f, 0.f, 0.f, 0.f};
            short8 b0 = *(const short8*)(fw + (cc * 2 + 0) * 512 + lane * 8);
            short8 b1 = *(const short8*)(fw + (cc * 2 + 1) * 512 + lane * 8);
            z4 = __builtin_amdgcn_mfma_f32_16x16x32_bf16(a0, b0, z4, 0, 0, 0);
            C1[cc] = __builtin_amdgcn_mfma_f32_16x16x32_bf16(a1, b1, z4, 0, 0, 0);
        }

        float pw[4] = {0.f, 0.f, 0.f, 0.f};
        #pragma unroll
        for (int cc = 0; cc < 4; ++cc) {
            float bt = b_dec[t * 64 + cc * 16 + c16];
            float wo = wov[cc];
            #pragma unroll
            for (int r = 0; r < 4; ++r) {
                float xx = C1[cc][r] + bt;            // C row(node)=g16*4+r, col=cc*16+c16
                float sp = xx > 0.f ? xx : 0.01f * xx;
                pw[r] = fmaf(sp, wo, pw[r]);
                zw[(g16 * 4 + r) * 72 + cc * 16 + c16] = f2b(sp);
            }
        }
        asm volatile("s_waitcnt lgkmcnt(0)" ::: "memory");
        short8 sa0 = *(const short8*)ab;
        short8 sa1 = *(const short8*)(ab + 32);

        float p1[4] = {0.f, 0.f, 0.f, 0.f};
        #pragma unroll
        for (int half = 0; half < 2; ++half) {
            float4v C2[4];
            #pragma unroll
            for (int cc = 0; cc < 4; ++cc) {
                int c8 = half * 4 + cc;
                float4v z4 = {0.f, 0.f, 0.f, 0.f};
                short8 b0 = *(const short8*)(fragWa1 + (c8 * 2 + 0) * 512 + lane * 8);
                short8 b1 = *(const short8*)(fragWa1 + (c8 * 2 + 1) * 512 + lane * 8);
                z4 = __builtin_amdgcn_mfma_f32_16x16x32_bf16(sa0, b0, z4, 0, 0, 0);
                C2[cc] = __builtin_amdgcn_mfma_f32_16x16x32_bf16(sa1, b1, z4, 0, 0, 0);
            }
            #pragma unroll
            for (int cc = 0; cc < 4; ++cc) {
                int c8 = half * 4 + cc;
                float ba = baw[c8], wa = waw[c8];
                #pragma unroll
                for (int r = 0; r < 4; ++r)
                    p1[r] = fmaf(fast_tanh(C2[cc][r] + ba), wa, p1[r]);
            }
        }

        #pragma unroll
        for (int mm = 1; mm < 16; mm <<= 1) {
            #pragma unroll
            for (int r = 0; r < 4; ++r) {
                p1[r] += __shfl_xor(p1[r], mm);
                pw[r] += __shfl_xor(pw[r], mm);
            }
        }

        if (c16 == 0) {
            #pragma unroll
            for (int r = 0; r < 4; ++r) {
                int n = nw + g16 * 4 + r;
                if (n < NF) {
                    S1[(size_t)t * NF + n] = p1[r];
                    PW[(size_t)t * NF + n] = pw[r];
                }
            }
        }
    }
}

// ---------------- 12-step scalar recurrence: 1 thread per node, table-lerp for s2 ----------------
__global__ __launch_bounds__(256) void dec_scan(
    const float* __restrict__ S1, const float* __restrict__ PW,
    const float* __restrict__ gtab, const float* __restrict__ uvs,
    const float* __restrict__ feat, const float* __restrict__ b_a2p,
    const float* __restrict__ b_op, float* __restrict__ out) {
    const int n = blockIdx.x * 256 + threadIdx.x;
    if (n >= NF) return;
    float s1v[12], pwv[12];
    #pragma unroll
    for (int t = 0; t < 12; ++t) {
        s1v[t] = S1[(size_t)t * NF + n];
        pwv[t] = PW[(size_t)t * NF + n];
    }
    const float wlo = uvs[256], blo = uvs[257], ba2 = b_a2p[0], bo = b_op[0];
    float yp = feat[n * 12 + 11];
    yp = (yp != yp) ? 0.f : yp;
    #pragma unroll
    for (int t = 0; t < 12; ++t) {
        float xf = fminf(fmaxf(fmaf(yp, 256.f, 8192.f), 0.f), 16383.f);
        int idx = (int)xf;
        float fr = xf - (float)idx;
        float g0 = gtab[idx], g1 = gtab[idx + 1];
        float p2 = fmaf(g1 - g0, fr, g0);
        float s1s = s1v[t] + ba2, s2s = p2 + ba2;
        float mx = fmaxf(s1s, s2s);
        float e1 = __expf(s1s - mx), e2 = __expf(s2s - mx);
        float y = (e1 * pwv[t] + e2 * fmaf(wlo, yp, blo)) / (e1 + e2) + bo;
        out[(size_t)t * NF + n] = y;
        yp = y;
    }
}

// ---------------- launch ----------------
extern "C" void kernel_launch(void* const* d_in, const int* in_sizes, int n_in,
                              void* d_out, int out_size, void* d_ws, size_t ws_size,
                              hipStream_t stream) {
    const float* feat   = (const float*)d_in[0];
    const int* enc_src  = (const int*)d_in[1];
    const int* enc_dst  = (const int*)d_in[2];
    const int* dec_src  = (const int*)d_in[3];
    const int* dec_dst  = (const int*)d_in[4];
    const float* W_enc  = (const float*)d_in[5];
    const float* b_enc  = (const float*)d_in[6];
    const float* W_proc = (const float*)d_in[7];
    const float* b_proc = (const float*)d_in[8];
    const float* W_dec  = (const float*)d_in[9];
    const float* b_dec  = (const float*)d_in[10];
    const float* W_lin  = (const float*)d_in[11];
    const float* b_lin  = (const float*)d_in[12];
    const float* W_a1   = (const float*)d_in[13];
    const float* b_a1   = (const float*)d_in[14];
    const float* W_a2   = (const float*)d_in[15];
    const float* b_a2   = (const float*)d_in[16];
    const float* W_o    = (const float*)d_in[17];
    const float* b_o    = (const float*)d_in[18];
    float* out = (float*)d_out;

    // layout: deg/cnt + csrD contiguous -> ONE zero memset.
    float* W = (float*)d_ws;
    float* deg_se   = W;                       // NF                 0 .. 100000
    float* deg_sd   = W + 100000;              // NH                 .. 149152
    int*   cntD     = (int*)(W + 149152);      // NF                 .. 249152
    int*   cntE     = (int*)(W + 249152);      // NH                 .. 298304
    u16*   csrD     = (u16*)(W + 298304);      // NF*24 u16 (1.2M u32) .. 1498304
    float* uvs      = W + 1498304;             // 260 -> pad         .. 1498624
    u16*   fragWdec = (u16*)(W + 1498624);     // 49152 u16          .. 1523200
    u16*   fragWa1  = (u16*)(W + 1523200);     // 8192 u16           .. 1527296
    float* agg      = W + 1527296;             // NH*16              .. 2313728
    float* S1       = W + 2313728;             // 12*NF              .. 3513728
    float* PW       = W + 3513728;             // 12*NF              .. 4713728
    u32*   csrE     = (u32*)(W + 4713728);     // NH*32              .. 6286592
    float* gtab     = W + 6286592;             // 16385 -> pad       .. 6303104
    u16*   m_ws     = (u16*)(W + 6303104);     // full: 3*(NH+1)*256 u16; fallback: (NH+1)*256 u16

    const size_t CSTRIDE = (size_t)(NH + 1) * 256;                       // u16 per chunk
    const size_t need_full = ((size_t)6303104 + 3 * CSTRIDE / 2) * 4;    // ~100.7 MB
    const bool full = ws_size >= need_full;
    const int zstride = full ? (int)(CSTRIDE / 2) : 0;                   // u32 units

    // ONE memset: deg_se/deg_sd/cntD/cntE + csrD (contiguous 6MB)
    hipMemsetAsync((void*)W, 0, (size_t)1498304 * 4, stream);

    // Kernel A: enc-graph atomics (+deg_sd) ∪ frag/uvs/gtab init ∪ m zero rows
    init_fill_enc<<<FILLB + 95, 256, 0, stream>>>(enc_src, enc_dst, dec_src,
                                                  cntE, csrE, deg_se, deg_sd,
                                                  W_dec, W_a1, fragWdec, fragWa1,
                                                  W_lin, b_lin, b_a1, W_o, uvs, W_a2, gtab,
                                                  (u32*)m_ws, zstride);

    const int dec_grid = (NF + 63) / 64;
    if (full) {
        // Kernel B: dec-graph atomics overlapped with encoder+m build
        enc_make_fill_dec<<<FILLB + NH / 4, 256, 0, stream>>>(dec_src, dec_dst, cntD, csrD,
                                                              feat, deg_se, cntE, csrE, deg_sd,
                                                              W_enc, b_enc, W_proc, b_proc,
                                                              m_ws, CSTRIDE);
        dec_batch<<<dim3(dec_grid, 3), 256, 0, stream>>>(m_ws, cntD, csrD, fragWdec, fragWa1,
                                                         b_dec, b_a1, W_a2, W_o, S1, PW,
                                                         0, CSTRIDE);
    } else {
        fill_dec<<<FILLB, 256, 0, stream>>>(dec_src, dec_dst, cntD, csrD);
        enc_gather<<<NH / 64, 256, 0, stream>>>(feat, deg_se, cntE, csrE, agg);
        for (int c = 0; c < 3; ++c) {
            make_chunk<<<(NH * 64) / 256, 256, 0, stream>>>(agg, cntE, deg_sd, W_enc, b_enc,
                                                            W_proc, b_proc, m_ws, 4 * c);
            dec_batch<<<dim3(dec_grid, 1), 256, 0, stream>>>(m_ws, cntD, csrD, fragWdec, fragWa1,
                                                             b_dec, b_a1, W_a2, W_o, S1, PW,
                                                             4 * c, 0);
        }
    }
    dec_scan<<<(NF + 255) / 256, 256, 0, stream>>>(S1, PW, gtab, uvs, feat, b_a2, b_o, out);
}

// Round 14
// 341.646 us; speedup vs baseline: 1.0234x; 1.0234x over previous
//
#include <hip/hip_runtime.h>
#include <hip/hip_bf16.h>
#include <hip/hip_fp16.h>

#define NF 100000
#define NH 49152
#define EDG 400000
#define SLOTD 24
#define SLOTE 32
#define FILLB 1563   /* (EDG+255)/256 */

typedef __attribute__((ext_vector_type(8))) short short8;
typedef __attribute__((ext_vector_type(4))) float float4v;
typedef unsigned short u16;
typedef unsigned int u32;

__device__ __forceinline__ u16 f2b(float x) {
    u32 u = __float_as_uint(x);
    u32 r = u + 0x7FFFu + ((u >> 16) & 1u);
    return (u16)(r >> 16);
}
// packed f32x2 -> bf16x2 in one VALU op (lo -> bits[15:0], hi -> bits[31:16])
__device__ __forceinline__ u32 cvt_pk(float lo, float hi) {
    u32 r;
    asm("v_cvt_pk_bf16_f32 %0, %1, %2" : "=v"(r) : "v"(lo), "v"(hi));
    return r;
}
__device__ __forceinline__ __half2 h2(u32 v) { union { u32 u; __half2 h; } c; c.u = v; return c.h; }
// 5-op tanh: exp2(x*2log2e) -> t; 1 - 2*rcp(t+1)
__device__ __forceinline__ float fast_tanh(float x) {
    float t = __builtin_amdgcn_exp2f(x * 2.885390081777927f);
    return fmaf(-2.0f, __builtin_amdgcn_rcpf(t + 1.0f), 1.0f);
}

// ---------------- Kernel A: fill_enc (atomics) ∪ init_small ∪ m zero rows ----------------
__global__ __launch_bounds__(256) void init_fill_enc(
    const int* __restrict__ enc_src, const int* __restrict__ enc_dst,
    const int* __restrict__ dec_src,
    int* __restrict__ cntE, u32* __restrict__ csrE,
    float* __restrict__ deg_se, float* __restrict__ deg_sd,
    const float* __restrict__ W_dec, const float* __restrict__ W_a1,
    u16* __restrict__ fragWdec, u16* __restrict__ fragWa1,
    const float* __restrict__ W_lin, const float* __restrict__ b_lin,
    const float* __restrict__ b_a1, const float* __restrict__ W_o,
    float* __restrict__ uvs, const float* __restrict__ W_a2,
    float* __restrict__ gtab, u32* __restrict__ mzero, int zstride) {
    __shared__ float uvl[256];
    const int b = blockIdx.x;
    if (b < FILLB) {
        int e = b * 256 + threadIdx.x;
        if (e >= EDG) return;
        int es = enc_src[e], ed = enc_dst[e], ds = dec_src[e];
        int i2 = atomicAdd(&cntE[ed], 1);
        atomicAdd(&deg_se[es], 1.0f);
        atomicAdd(&deg_sd[ds], 1.0f);
        if (i2 < SLOTE) csrE[(size_t)ed * SLOTE + i2] = (u32)es;
        return;
    }
    const int b2 = b - FILLB;
    if (b2 < 28) {
        int gid = b2 * 256 + threadIdx.x;   // 0..7167
        if (gid >= 7168) return;
        int L = gid & 63;
        int f = gid >> 6;          // 0..95: W_dec (t=f>>3); 96..111: W_a1
        int q = L >> 4, cb = L & 15;
        if (f < 96) {
            int fr = f & 7;
            int c = fr >> 1, kc = fr & 1;
            int k0 = kc * 32 + q * 8;
            int nn = c * 16 + cb;
            int t = f >> 3;
            #pragma unroll
            for (int j = 0; j < 8; ++j)
                fragWdec[(f * 64 + L) * 8 + j] = f2b(W_dec[t * 4096 + (k0 + j) * 64 + nn]);
        } else {
            int fr = f - 96;
            int c2 = fr >> 1, kc = fr & 1;
            int k0 = kc * 32 + q * 8;
            int nn = c2 * 16 + cb;
            #pragma unroll
            for (int j = 0; j < 8; ++j)
                fragWa1[(fr * 64 + L) * 8 + j] = f2b(W_a1[(k0 + j) * 128 + nn]);
        }
    } else if (b2 == 28) {
        // uvs for dec_scan
        int k = threadIdx.x;
        if (k < 128) {
            float su = 0.f, sv = 0.f;
            for (int h = 0; h < 64; ++h) {
                su = fmaf(W_lin[h], W_a1[h * 128 + k], su);
                sv = fmaf(b_lin[h], W_a1[h * 128 + k], sv);
            }
            uvs[k] = su;
            uvs[128 + k] = sv + b_a1[k];
            if (k == 0) {
                float a = 0.f, bb = 0.f;
                for (int h = 0; h < 64; ++h) {
                    a = fmaf(W_lin[h], W_o[h], a);
                    bb = fmaf(b_lin[h], W_o[h], bb);
                }
                uvs[256] = a;  // wlo
                uvs[257] = bb; // blo
            }
        }
    } else if (b2 == 94) {
        // zero the 3 chunk zero-rows of m (384 u32 total; zstride=0 in fallback)
        for (int j = threadIdx.x; j < 384; j += 256)
            mzero[(j >> 7) * (size_t)zstride + (j & 127)] = 0u;
    } else {
        // gtab blocks (b2 = 29..93): recompute u,v locally (no cross-block dependency)
        int k = threadIdx.x;
        if (k < 128) {
            float su = 0.f, sv = 0.f;
            for (int h = 0; h < 64; ++h) {
                su = fmaf(W_lin[h], W_a1[h * 128 + k], su);
                sv = fmaf(b_lin[h], W_a1[h * 128 + k], sv);
            }
            uvl[k] = su;
            uvl[128 + k] = sv + b_a1[k];
        }
        __syncthreads();
        int i = (b2 - 29) * 256 + threadIdx.x;
        if (i <= 16384) {
            float y = fmaf((float)i, 1.f / 256.f, -32.f);
            float s = 0.f;
            for (int kk = 0; kk < 128; ++kk)
                s = fmaf(fast_tanh(fmaf(y, uvl[kk], uvl[128 + kk])), W_a2[kk], s);
            gtab[i] = s;
        }
    }
}

// ---------------- standalone fill_dec (fallback path) ----------------
__global__ void fill_dec(const int* __restrict__ dec_src, const int* __restrict__ dec_dst,
                         int* __restrict__ cntD, u16* __restrict__ csrD) {
    int e = blockIdx.x * 256 + threadIdx.x;
    if (e >= EDG) return;
    int ds = dec_src[e], dd = dec_dst[e];
    int i1 = atomicAdd(&cntD[dd], 1);
    if (i1 < SLOTD) csrD[(size_t)dd * SLOTD + i1] = (u16)(ds + 1);   // 0 = empty
}

// ---------------- Kernel B: fill_dec (blocks 0..FILLB-1) ∪ enc_make ----------------
__global__ __launch_bounds__(256) void enc_make_fill_dec(
    const int* __restrict__ dec_src, const int* __restrict__ dec_dst,
    int* __restrict__ cntD, u16* __restrict__ csrD,
    const float* __restrict__ feat, const float* __restrict__ deg_se,
    const int* __restrict__ cntE, const u32* __restrict__ csrE,
    const float* __restrict__ deg_sd, const float* __restrict__ W_enc,
    const float* __restrict__ b_enc, const float* __restrict__ W_proc,
    const float* __restrict__ b_proc, u16* __restrict__ m, size_t cstride) {
    __shared__ __align__(16) float aggl[4][12];
    const int b = blockIdx.x;
    if (b < FILLB) {
        int e = b * 256 + threadIdx.x;
        if (e >= EDG) return;
        int ds = dec_src[e], dd = dec_dst[e];
        int i1 = atomicAdd(&cntD[dd], 1);
        if (i1 < SLOTD) csrD[(size_t)dd * SLOTD + i1] = (u16)(ds + 1);
        return;
    }
    const int tid = threadIdx.x, lane = tid & 63, wid = tid >> 6;
    const int n = (b - FILLB) * 4 + wid;          // one node per wave
    const int q = lane >> 2, l = lane & 3;        // 16 edge slots x 4 lanes
    int cntRaw = cntE[n];
    int cnt = cntRaw > SLOTE ? SLOTE : cntRaw;
    const u32* cp = csrE + (size_t)n * SLOTE;
    float4 a = {0.f, 0.f, 0.f, 0.f};
    if (l < 3) {
        for (int e = q; e < cnt; e += 16) {
            u32 s = cp[e];
            float c = rsqrtf(fmaxf(deg_se[s], 1.0f));
            float4 w = *(const float4*)(feat + (size_t)s * 12 + l * 4);
            w.x = (w.x != w.x) ? 0.f : w.x; w.y = (w.y != w.y) ? 0.f : w.y;
            w.z = (w.z != w.z) ? 0.f : w.z; w.w = (w.w != w.w) ? 0.f : w.w;
            a.x = fmaf(w.x, c, a.x); a.y = fmaf(w.y, c, a.y);
            a.z = fmaf(w.z, c, a.z); a.w = fmaf(w.w, c, a.w);
        }
    }
    // reduce across the 16 slots (lane bits 2..5)
    #pragma unroll
    for (int mm = 4; mm < 64; mm <<= 1) {
        a.x += __shfl_xor(a.x, mm); a.y += __shfl_xor(a.y, mm);
        a.z += __shfl_xor(a.z, mm); a.w += __shfl_xor(a.w, mm);
    }
    if (q == 0 && l < 3) *(float4*)(&aggl[wid][l * 4]) = a;
    asm volatile("s_waitcnt lgkmcnt(0)" ::: "memory");   // wave-local LDS ready

    const int h = lane;
    float cde = rsqrtf(fmaxf((float)cntRaw, 1.0f));
    float csd = rsqrtf(fmaxf(deg_sd[n], 1.0f));
    float he[12];
    #pragma unroll
    for (int ti = 0; ti < 12; ++ti) {
        float av = aggl[wid][ti] * cde;
        float x = fmaf(av, W_enc[ti * 64 + h], b_enc[ti * 64 + h]);
        he[ti] = x > 0.f ? x : 0.01f * x;
    }
    #pragma unroll
    for (int c = 0; c < 3; ++c) {
        float s0v[4];
        #pragma unroll
        for (int tt = 0; tt < 4; ++tt) {
            int t = c * 4 + tt;
            float s = b_proc[t];
            #pragma unroll
            for (int ti = 0; ti < 12; ++ti) s = fmaf(he[ti], W_proc[ti * 12 + t], s);
            s0v[tt] = fmaxf(s, 0.f) * csd;
        }
        u16 r0 = __half_as_ushort(__float2half(s0v[0]));
        u16 r1 = __half_as_ushort(__float2half(s0v[1]));
        u16 r2 = __half_as_ushort(__float2half(s0v[2]));
        u16 r3 = __half_as_ushort(__float2half(s0v[3]));
        u32 o0 = ((u32)r1 << 16) | r0;
        u32 o1 = ((u32)r3 << 16) | r2;
        u32* dst = (u32*)(m + c * cstride + (size_t)(n + 1) * 256 + h * 4);
        dst[0] = o0; dst[1] = o1;
    }
}

// ---------------- fallback pieces (small-workspace path) ----------------
__global__ __launch_bounds__(256) void enc_gather(const float* __restrict__ feat,
                                                  const float* __restrict__ deg_se,
                                                  const int* __restrict__ cntE,
                                                  const u32* __restrict__ csrE,
                                                  float* __restrict__ agg) {
    const int tid = threadIdx.x, lane = tid & 63, wid = tid >> 6;
    const int grp = lane >> 2, l = lane & 3;      // 16 quads of 4 lanes
    const int dst = blockIdx.x * 64 + wid * 16 + grp;
    int cnt = cntE[dst];
    if (cnt > SLOTE) cnt = SLOTE;
    const u32* cp = csrE + (size_t)dst * SLOTE;
    float4 a = {0.f, 0.f, 0.f, 0.f};
    if (l < 3) {
        for (int e = 0; e < cnt; ++e) {
            u32 s = cp[e];
            float c = rsqrtf(fmaxf(deg_se[s], 1.0f));
            float4 w = *(const float4*)(feat + (size_t)s * 12 + l * 4);
            w.x = (w.x != w.x) ? 0.f : w.x; w.y = (w.y != w.y) ? 0.f : w.y;
            w.z = (w.z != w.z) ? 0.f : w.z; w.w = (w.w != w.w) ? 0.f : w.w;
            a.x = fmaf(w.x, c, a.x); a.y = fmaf(w.y, c, a.y);
            a.z = fmaf(w.z, c, a.z); a.w = fmaf(w.w, c, a.w);
        }
    }
    *(float4*)(agg + (size_t)dst * 16 + l * 4) = a;   // l==3 writes zero pad
}

__global__ void make_chunk(const float* __restrict__ agg, const int* __restrict__ cntE,
                           const float* __restrict__ deg_sd, const float* __restrict__ W_enc,
                           const float* __restrict__ b_enc, const float* __restrict__ W_proc,
                           const float* __restrict__ b_proc, u16* __restrict__ m, int t0) {
    int gid = blockIdx.x * 256 + threadIdx.x;
    if (gid >= NH * 64) return;
    int n = gid >> 6, h = gid & 63;
    float cde = rsqrtf(fmaxf((float)cntE[n], 1.0f));
    float csd = rsqrtf(fmaxf(deg_sd[n], 1.0f));
    float he[12];
    #pragma unroll
    for (int ti = 0; ti < 12; ++ti) {
        float a = agg[n * 16 + ti] * cde;
        float x = fmaf(a, W_enc[ti * 64 + h], b_enc[ti * 64 + h]);
        he[ti] = x > 0.f ? x : 0.01f * x;
    }
    u16 r[4];
    #pragma unroll
    for (int tt = 0; tt < 4; ++tt) {
        int t = t0 + tt;
        float s = b_proc[t];
        #pragma unroll
        for (int ti = 0; ti < 12; ++ti) s = fmaf(he[ti], W_proc[ti * 12 + t], s);
        s = fmaxf(s, 0.f) * csd;
        r[tt] = __half_as_ushort(__float2half(s));
    }
    u32 o0 = ((u32)r[1] << 16) | r[0];
    u32 o1 = ((u32)r[3] << 16) | r[2];
    u32* dst = (u32*)(m + (size_t)(n + 1) * 256 + h * 4);
    dst[0] = o0; dst[1] = o1;
}

// 4-edge accumulate helper (a8 = 8 half2 channels for one node); s==0 -> zero row
__device__ __forceinline__ void acc4(__half2* a8, const u16* mrow, u32 lo, u32 hi) {
    int s0 = (int)(lo & 0xFFFF), s1 = (int)(lo >> 16);
    int s2 = (int)(hi & 0xFFFF), s3 = (int)(hi >> 16);
    const uint4* r0 = (const uint4*)(mrow + (size_t)s0 * 256);
    const uint4* r1 = (const uint4*)(mrow + (size_t)s1 * 256);
    const uint4* r2 = (const uint4*)(mrow + (size_t)s2 * 256);
    const uint4* r3 = (const uint4*)(mrow + (size_t)s3 * 256);
    uint4 A0 = r0[0], B0 = r0[1];
    uint4 A1 = r1[0], B1 = r1[1];
    uint4 A2 = r2[0], B2 = r2[1];
    uint4 A3 = r3[0], B3 = r3[1];
    a8[0] = __hadd2(a8[0], __hadd2(__hadd2(h2(A0.x), h2(A1.x)), __hadd2(h2(A2.x), h2(A3.x))));
    a8[1] = __hadd2(a8[1], __hadd2(__hadd2(h2(A0.y), h2(A1.y)), __hadd2(h2(A2.y), h2(A3.y))));
    a8[2] = __hadd2(a8[2], __hadd2(__hadd2(h2(A0.z), h2(A1.z)), __hadd2(h2(A2.z), h2(A3.z))));
    a8[3] = __hadd2(a8[3], __hadd2(__hadd2(h2(A0.w), h2(A1.w)), __hadd2(h2(A2.w), h2(A3.w))));
    a8[4] = __hadd2(a8[4], __hadd2(__hadd2(h2(B0.x), h2(B1.x)), __hadd2(h2(B2.x), h2(B3.x))));
    a8[5] = __hadd2(a8[5], __hadd2(__hadd2(h2(B0.y), h2(B1.y)), __hadd2(h2(B2.y), h2(B3.y))));
    a8[6] = __hadd2(a8[6], __hadd2(__hadd2(h2(B0.z), h2(B1.z)), __hadd2(h2(B2.z), h2(B3.z))));
    a8[7] = __hadd2(a8[7], __hadd2(__hadd2(h2(B0.w), h2(B1.w)), __hadd2(h2(B2.w), h2(B3.w))));
}

// ---------------- decoder pass: chunk = blockIdx.y; gather + MFMA GEMMs ----------------
// R14: exact R12-proven body (140.3us, VGPR 60, no spill): guarded window 0
// (unconditional variant spills — R13; 5-wave occupancy spills — R6). Single
// (dec_grid,3) dispatch, 4-buffer stride-72 LDS, (256,4), cvt_pk, 5-op tanh,
// hoisted weights, csrD +1 scheme (0 = empty -> zero row 0).
__global__ __launch_bounds__(256, 4) void dec_batch(
    const u16* __restrict__ mbase, const int* __restrict__ cntD, const u16* __restrict__ csrD,
    const u16* __restrict__ fragWdec, const u16* __restrict__ fragWa1,
    const float* __restrict__ b_dec, const float* __restrict__ b_a1,
    const float* __restrict__ W_a2, const float* __restrict__ W_o,
    float* __restrict__ S1, float* __restrict__ PW, int t0p, size_t mstride) {
    __shared__ __align__(16) u16 zs[18432];   // 4 waves x (4 tt x 16 rows x 72)

    const u16* m = mbase + (size_t)blockIdx.y * mstride;
    const int t0 = t0p + blockIdx.y * 4;
    const int tid = threadIdx.x, lane = tid & 63, wid = tid >> 6;
    const int nw = blockIdx.x * 64 + wid * 16;
    const int g16 = lane >> 4, c16 = lane & 15;
    u16* zw0 = zs + wid * 4608;

    // ---- per-node metadata + first CSR window (8 edges) ----
    int cdw[4]; float cdd[4]; int nnv[4];
    uint4 qa[4];
    #pragma unroll
    for (int k = 0; k < 4; ++k) {
        int n = nw + g16 * 4 + k;
        bool v = (n < NF);
        nnv[k] = v ? n : 0;
        int cd = cntD[nnv[k]];
        cdd[k] = v ? rsqrtf(fmaxf((float)cd, 1.0f)) : 0.f;
        cdw[k] = v ? (cd > SLOTD ? SLOTD : cd) : 0;
        qa[k] = *(const uint4*)(csrD + (size_t)nnv[k] * SLOTD);
    }
    int cdmax = max(max(cdw[0], cdw[1]), max(cdw[2], cdw[3]));

    // acc[k][ch*2 + p]: node k, channel c16*4+ch, tt-pair p
    __half2 acc[4][8];
    #pragma unroll
    for (int k = 0; k < 4; ++k)
        #pragma unroll
        for (int i = 0; i < 8; ++i)
            acc[k][i] = __half2{__half(0.f), __half(0.f)};

    const u16* mrow = m + c16 * 16;
    // window 0: edges 0..7 (empty slots = 0 -> zero row; guards keep VGPR <= 60)
    #pragma unroll
    for (int k = 0; k < 4; ++k) if (cdw[k] > 0) acc4(acc[k], mrow, qa[k].x, qa[k].y);
    #pragma unroll
    for (int k = 0; k < 4; ++k) if (cdw[k] > 4) acc4(acc[k], mrow, qa[k].z, qa[k].w);
    if (__any(cdmax > 8)) {
        // window 1: edges 8..15 (reuse qa registers)
        #pragma unroll
        for (int k = 0; k < 4; ++k) if (cdw[k] > 8) qa[k] = *(const uint4*)(csrD + (size_t)nnv[k] * SLOTD + 8);
        #pragma unroll
        for (int k = 0; k < 4; ++k) if (cdw[k] > 8) acc4(acc[k], mrow, qa[k].x, qa[k].y);
        #pragma unroll
        for (int k = 0; k < 4; ++k) if (cdw[k] > 12) acc4(acc[k], mrow, qa[k].z, qa[k].w);
        if (__any(cdmax > 16)) {
            // window 2: edges 16..23
            #pragma unroll
            for (int k = 0; k < 4; ++k) if (cdw[k] > 16) qa[k] = *(const uint4*)(csrD + (size_t)nnv[k] * SLOTD + 16);
            #pragma unroll
            for (int k = 0; k < 4; ++k) if (cdw[k] > 16) acc4(acc[k], mrow, qa[k].x, qa[k].y);
            #pragma unroll
            for (int k = 0; k < 4; ++k) if (cdw[k] > 20) acc4(acc[k], mrow, qa[k].z, qa[k].w);
        }
    }

    // ---- stage all 4 tt into LDS (A-operand layout per tt, stride 72) ----
    #pragma unroll
    for (int k = 0; k < 4; ++k) {
        int j = g16 * 4 + k;
        float s = cdd[k];
        #pragma unroll
        for (int p = 0; p < 2; ++p) {
            float2 c0 = __half22float2(acc[k][0 * 2 + p]);
            float2 c1 = __half22float2(acc[k][1 * 2 + p]);
            float2 c2 = __half22float2(acc[k][2 * 2 + p]);
            float2 c3 = __half22float2(acc[k][3 * 2 + p]);
            u32 oA0 = cvt_pk(c0.x * s, c1.x * s);
            u32 oA1 = cvt_pk(c2.x * s, c3.x * s);
            u32 oB0 = cvt_pk(c0.y * s, c1.y * s);
            u32 oB1 = cvt_pk(c2.y * s, c3.y * s);
            u32* dA = (u32*)(zw0 + (2 * p) * 1152 + j * 72 + c16 * 4);
            u32* dB = (u32*)(zw0 + (2 * p + 1) * 1152 + j * 72 + c16 * 4);
            dA[0] = oA0; dA[1] = oA1;
            dB[0] = oB0; dB[1] = oB1;
        }
    }
    asm volatile("s_waitcnt lgkmcnt(0)" ::: "memory");   // wave-local zs ready

    // ---- t-invariant per-lane weights hoisted out of the tt loop ----
    float baw[8], waw[8], wov[4];
    #pragma unroll
    for (int c8 = 0; c8 < 8; ++c8) {
        int k = c8 * 16 + c16;
        baw[c8] = b_a1[k];
        waw[c8] = W_a2[k];
    }
    #pragma unroll
    for (int cc = 0; cc < 4; ++cc) wov[cc] = W_o[cc * 16 + c16];

    // ---- per-t GEMM pipeline (B-fragments streamed from L2; no __syncthreads) ----
    for (int tt = 0; tt < 4; ++tt) {
        const int t = t0 + tt;
        u16* zw = zw0 + tt * 1152;
        const u16* ab = zw + c16 * 72 + g16 * 8;
        short8 a0 = *(const short8*)ab;            // A[m=c16][k=g16*8+j]
        short8 a1 = *(const short8*)(ab + 32);     // k += 32

        const u16* fw = fragWdec + (size_t)t * 4096;
        float4v C1[4];
        #pragma unroll
        for (int cc = 0; cc < 4; ++cc) {
            float4v z4 = {0.f, 0.f, 0.f, 0.f};
            short8 b0 = *(const short8*)(fw + (cc * 2 + 0) * 512 + lane * 8);
            short8 b1 = *(const short8*)(fw + (cc * 2 + 1) * 512 + lane * 8);
            z4 = __builtin_amdgcn_mfma_f32_16x16x32_bf16(a0, b0, z4, 0, 0, 0);
            C1[cc] = __builtin_amdgcn_mfma_f32_16x16x32_bf16(a1, b1, z4, 0, 0, 0);
        }

        float pw[4] = {0.f, 0.f, 0.f, 0.f};
        #pragma unroll
        for (int cc = 0; cc < 4; ++cc) {
            float bt = b_dec[t * 64 + cc * 16 + c16];
            float wo = wov[cc];
            #pragma unroll
            for (int r = 0; r < 4; ++r) {
                float xx = C1[cc][r] + bt;            // C row(node)=g16*4+r, col=cc*16+c16
                float sp = xx > 0.f ? xx : 0.01f * xx;
                pw[r] = fmaf(sp, wo, pw[r]);
                zw[(g16 * 4 + r) * 72 + cc * 16 + c16] = f2b(sp);
            }
        }
        asm volatile("s_waitcnt lgkmcnt(0)" ::: "memory");
        short8 sa0 = *(const short8*)ab;
        short8 sa1 = *(const short8*)(ab + 32);

        float p1[4] = {0.f, 0.f, 0.f, 0.f};
        #pragma unroll
        for (int half = 0; half < 2; ++half) {
            float4v C2[4];
            #pragma unroll
            for (int cc = 0; cc < 4; ++cc) {
                int c8 = half * 4 + cc;
                float4v z4 = {0.f, 0.f, 0.f, 0.f};
                short8 b0 = *(const short8*)(fragWa1 + (c8 * 2 + 0) * 512 + lane * 8);
                short8 b1 = *(const short8*)(fragWa1 + (c8 * 2 + 1) * 512 + lane * 8);
                z4 = __builtin_amdgcn_mfma_f32_16x16x32_bf16(sa0, b0, z4, 0, 0, 0);
                C2[cc] = __builtin_amdgcn_mfma_f32_16x16x32_bf16(sa1, b1, z4, 0, 0, 0);
            }
            #pragma unroll
            for (int cc = 0; cc < 4; ++cc) {
                int c8 = half * 4 + cc;
                float ba = baw[c8], wa = waw[c8];
                #pragma unroll
                for (int r = 0; r < 4; ++r)
                    p1[r] = fmaf(fast_tanh(C2[cc][r] + ba), wa, p1[r]);
            }
        }

        #pragma unroll
        for (int mm = 1; mm < 16; mm <<= 1) {
            #pragma unroll
            for (int r = 0; r < 4; ++r) {
                p1[r] += __shfl_xor(p1[r], mm);
                pw[r] += __shfl_xor(pw[r], mm);
            }
        }

        if (c16 == 0) {
            #pragma unroll
            for (int r = 0; r < 4; ++r) {
                int n = nw + g16 * 4 + r;
                if (n < NF) {
                    S1[(size_t)t * NF + n] = p1[r];
                    PW[(size_t)t * NF + n] = pw[r];
                }
            }
        }
    }
}

// ---------------- 12-step scalar recurrence: 1 thread per node, table-lerp for s2 ----------------
__global__ __launch_bounds__(256) void dec_scan(
    const float* __restrict__ S1, const float* __restrict__ PW,
    const float* __restrict__ gtab, const float* __restrict__ uvs,
    const float* __restrict__ feat, const float* __restrict__ b_a2p,
    const float* __restrict__ b_op, float* __restrict__ out) {
    const int n = blockIdx.x * 256 + threadIdx.x;
    if (n >= NF) return;
    float s1v[12], pwv[12];
    #pragma unroll
    for (int t = 0; t < 12; ++t) {
        s1v[t] = S1[(size_t)t * NF + n];
        pwv[t] = PW[(size_t)t * NF + n];
    }
    const float wlo = uvs[256], blo = uvs[257], ba2 = b_a2p[0], bo = b_op[0];
    float yp = feat[n * 12 + 11];
    yp = (yp != yp) ? 0.f : yp;
    #pragma unroll
    for (int t = 0; t < 12; ++t) {
        float xf = fminf(fmaxf(fmaf(yp, 256.f, 8192.f), 0.f), 16383.f);
        int idx = (int)xf;
        float fr = xf - (float)idx;
        float g0 = gtab[idx], g1 = gtab[idx + 1];
        float p2 = fmaf(g1 - g0, fr, g0);
        float s1s = s1v[t] + ba2, s2s = p2 + ba2;
        float mx = fmaxf(s1s, s2s);
        float e1 = __expf(s1s - mx), e2 = __expf(s2s - mx);
        float y = (e1 * pwv[t] + e2 * fmaf(wlo, yp, blo)) / (e1 + e2) + bo;
        out[(size_t)t * NF + n] = y;
        yp = y;
    }
}

// ---------------- launch ----------------
extern "C" void kernel_launch(void* const* d_in, const int* in_sizes, int n_in,
                              void* d_out, int out_size, void* d_ws, size_t ws_size,
                              hipStream_t stream) {
    const float* feat   = (const float*)d_in[0];
    const int* enc_src  = (const int*)d_in[1];
    const int* enc_dst  = (const int*)d_in[2];
    const int* dec_src  = (const int*)d_in[3];
    const int* dec_dst  = (const int*)d_in[4];
    const float* W_enc  = (const float*)d_in[5];
    const float* b_enc  = (const float*)d_in[6];
    const float* W_proc = (const float*)d_in[7];
    const float* b_proc = (const float*)d_in[8];
    const float* W_dec  = (const float*)d_in[9];
    const float* b_dec  = (const float*)d_in[10];
    const float* W_lin  = (const float*)d_in[11];
    const float* b_lin  = (const float*)d_in[12];
    const float* W_a1   = (const float*)d_in[13];
    const float* b_a1   = (const float*)d_in[14];
    const float* W_a2   = (const float*)d_in[15];
    const float* b_a2   = (const float*)d_in[16];
    const float* W_o    = (const float*)d_in[17];
    const float* b_o    = (const float*)d_in[18];
    float* out = (float*)d_out;

    // layout: deg/cnt + csrD contiguous -> ONE zero memset.
    float* W = (float*)d_ws;
    float* deg_se   = W;                       // NF                 0 .. 100000
    float* deg_sd   = W + 100000;              // NH                 .. 149152
    int*   cntD     = (int*)(W + 149152);      // NF                 .. 249152
    int*   cntE     = (int*)(W + 249152);      // NH                 .. 298304
    u16*   csrD     = (u16*)(W + 298304);      // NF*24 u16 (1.2M u32) .. 1498304
    float* uvs      = W + 1498304;             // 260 -> pad         .. 1498624
    u16*   fragWdec = (u16*)(W + 1498624);     // 49152 u16          .. 1523200
    u16*   fragWa1  = (u16*)(W + 1523200);     // 8192 u16           .. 1527296
    float* agg      = W + 1527296;             // NH*16              .. 2313728
    float* S1       = W + 2313728;             // 12*NF              .. 3513728
    float* PW       = W + 3513728;             // 12*NF              .. 4713728
    u32*   csrE     = (u32*)(W + 4713728);     // NH*32              .. 6286592
    float* gtab     = W + 6286592;             // 16385 -> pad       .. 6303104
    u16*   m_ws     = (u16*)(W + 6303104);     // full: 3*(NH+1)*256 u16; fallback: (NH+1)*256 u16

    const size_t CSTRIDE = (size_t)(NH + 1) * 256;                       // u16 per chunk
    const size_t need_full = ((size_t)6303104 + 3 * CSTRIDE / 2) * 4;    // ~100.7 MB
    const bool full = ws_size >= need_full;
    const int zstride = full ? (int)(CSTRIDE / 2) : 0;                   // u32 units

    // ONE memset: deg_se/deg_sd/cntD/cntE + csrD (contiguous 6MB)
    hipMemsetAsync((void*)W, 0, (size_t)1498304 * 4, stream);

    // Kernel A: enc-graph atomics (+deg_sd) ∪ frag/uvs/gtab init ∪ m zero rows
    init_fill_enc<<<FILLB + 95, 256, 0, stream>>>(enc_src, enc_dst, dec_src,
                                                  cntE, csrE, deg_se, deg_sd,
                                                  W_dec, W_a1, fragWdec, fragWa1,
                                                  W_lin, b_lin, b_a1, W_o, uvs, W_a2, gtab,
                                                  (u32*)m_ws, zstride);

    const int dec_grid = (NF + 63) / 64;
    if (full) {
        // Kernel B: dec-graph atomics overlapped with encoder+m build
        enc_make_fill_dec<<<FILLB + NH / 4, 256, 0, stream>>>(dec_src, dec_dst, cntD, csrD,
                                                              feat, deg_se, cntE, csrE, deg_sd,
                                                              W_enc, b_enc, W_proc, b_proc,
                                                              m_ws, CSTRIDE);
        dec_batch<<<dim3(dec_grid, 3), 256, 0, stream>>>(m_ws, cntD, csrD, fragWdec, fragWa1,
                                                         b_dec, b_a1, W_a2, W_o, S1, PW,
                                                         0, CSTRIDE);
    } else {
        fill_dec<<<FILLB, 256, 0, stream>>>(dec_src, dec_dst, cntD, csrD);
        enc_gather<<<NH / 64, 256, 0, stream>>>(feat, deg_se, cntE, csrE, agg);
        for (int c = 0; c < 3; ++c) {
            make_chunk<<<(NH * 64) / 256, 256, 0, stream>>>(agg, cntE, deg_sd, W_enc, b_enc,
                                                            W_proc, b_proc, m_ws, 4 * c);
            dec_batch<<<dim3(dec_grid, 1), 256, 0, stream>>>(m_ws, cntD, csrD, fragWdec, fragWa1,
                                                             b_dec, b_a1, W_a2, W_o, S1, PW,
                                                             4 * c, 0);
        }
    }
    dec_scan<<<(NF + 255) / 256, 256, 0, stream>>>(S1, PW, gtab, uvs, feat, b_a2, b_o, out);
}